// Round 1
// baseline (212.089 us; speedup 1.0000x reference)
//
#include <hip/hip_runtime.h>
#include <cmath>

#define IN_DIM 64

__global__ void node_scores_kernel(const float* __restrict__ h,
                                   const float* __restrict__ gate_w,
                                   const float* __restrict__ gate_b,
                                   float* __restrict__ sD,
                                   float* __restrict__ sS,
                                   int n_nodes) {
    int gid  = blockIdx.x * blockDim.x + threadIdx.x;
    int node = gid >> 6;           // one 64-lane wave per node
    int lane = threadIdx.x & 63;
    if (node >= n_nodes) return;

    float hv = h[node * IN_DIM + lane];
    float pd = hv * gate_w[lane];            // w_dst = gate_w[:64]
    float ps = hv * gate_w[IN_DIM + lane];   // w_src = gate_w[64:]

    // butterfly reduce across the 64-lane wave
    #pragma unroll
    for (int off = 32; off > 0; off >>= 1) {
        pd += __shfl_xor(pd, off, 64);
        ps += __shfl_xor(ps, off, 64);
    }
    if (lane == 0) {
        sD[node] = pd + gate_b[0];   // fold bias into s_dst
        sS[node] = ps;
    }
}

__global__ void edge_scatter_kernel(const float* __restrict__ h,
                                    const float* __restrict__ d,
                                    const int* __restrict__ src,
                                    const int* __restrict__ dst,
                                    const float* __restrict__ sD,
                                    const float* __restrict__ sS,
                                    float* __restrict__ z,
                                    int n_edges) {
    int gid  = blockIdx.x * blockDim.x + threadIdx.x;
    int e    = gid >> 6;           // one 64-lane wave per edge
    int lane = threadIdx.x & 63;
    if (e >= n_edges) return;

    int s = src[e];
    int t = dst[e];
    // wave-uniform scalar loads (same address across lanes -> broadcast)
    float g = tanhf(sD[t] + sS[s]);
    float c = g * d[t] * d[s];

    // coalesced gather of h[s] and coalesced atomics into z[t]
    atomicAdd(&z[t * IN_DIM + lane], h[s * IN_DIM + lane] * c);
}

extern "C" void kernel_launch(void* const* d_in, const int* in_sizes, int n_in,
                              void* d_out, int out_size, void* d_ws, size_t ws_size,
                              hipStream_t stream) {
    const float* h      = (const float*)d_in[0];
    const float* d      = (const float*)d_in[1];
    const int*   src    = (const int*)d_in[2];
    const int*   dst    = (const int*)d_in[3];
    const float* gate_w = (const float*)d_in[4];
    const float* gate_b = (const float*)d_in[5];

    const int n_nodes = in_sizes[1];   // d has one element per node
    const int n_edges = in_sizes[2];   // src has one element per edge

    float* sD = (float*)d_ws;
    float* sS = sD + n_nodes;

    float* z = (float*)d_out;

    // zero the output accumulator (harness poisons it with 0xAA)
    hipMemsetAsync(z, 0, (size_t)out_size * sizeof(float), stream);

    {
        int total   = n_nodes * 64;
        int threads = 256;
        int blocks  = (total + threads - 1) / threads;
        node_scores_kernel<<<blocks, threads, 0, stream>>>(h, gate_w, gate_b, sD, sS, n_nodes);
    }
    {
        long long total = (long long)n_edges * 64;
        int threads = 256;
        long long blocks = (total + threads - 1) / threads;
        edge_scatter_kernel<<<(int)blocks, threads, 0, stream>>>(h, d, src, dst, sD, sS, z, n_edges);
    }
}

// Round 2
// 184.770 us; speedup vs baseline: 1.1479x; 1.1479x over previous
//
#include <hip/hip_runtime.h>
#include <cmath>

#define IN_DIM 64
#define SCAN_CHUNK 256

// ---------------- node scores: s_dst/s_src per node (wave per node) ---------
__global__ void node_scores_kernel(const float* __restrict__ h,
                                   const float* __restrict__ gate_w,
                                   const float* __restrict__ gate_b,
                                   float* __restrict__ sD,
                                   float* __restrict__ sS,
                                   int n_nodes) {
    int gid  = blockIdx.x * blockDim.x + threadIdx.x;
    int node = gid >> 6;
    int lane = threadIdx.x & 63;
    if (node >= n_nodes) return;

    float hv = h[node * IN_DIM + lane];
    float pd = hv * gate_w[lane];            // w_dst = gate_w[:64]
    float ps = hv * gate_w[IN_DIM + lane];   // w_src = gate_w[64:]

    #pragma unroll
    for (int off = 32; off > 0; off >>= 1) {
        pd += __shfl_xor(pd, off, 64);
        ps += __shfl_xor(ps, off, 64);
    }
    if (lane == 0) {
        sD[node] = pd + gate_b[0];   // bias folded into s_dst
        sS[node] = ps;
    }
}

// ---------------- histogram of dst ------------------------------------------
__global__ void hist_kernel(const int* __restrict__ dst, int* __restrict__ cnt,
                            int n_edges) {
    int e = blockIdx.x * blockDim.x + threadIdx.x;
    if (e < n_edges) atomicAdd(&cnt[dst[e]], 1);
}

// ---------------- 3-step exclusive scan over n_nodes counters ---------------
__global__ void scan_blocks_kernel(const int* __restrict__ cnt,
                                   int* __restrict__ off,
                                   int* __restrict__ bsum, int n) {
    __shared__ int sm[SCAN_CHUNK];
    int tid = threadIdx.x;
    int gid = blockIdx.x * SCAN_CHUNK + tid;
    int v = (gid < n) ? cnt[gid] : 0;
    sm[tid] = v;
    __syncthreads();
    for (int o = 1; o < SCAN_CHUNK; o <<= 1) {
        int t = (tid >= o) ? sm[tid - o] : 0;
        __syncthreads();
        sm[tid] += t;
        __syncthreads();
    }
    if (gid < n) off[gid] = sm[tid] - v;                 // block-local exclusive
    if (tid == SCAN_CHUNK - 1) bsum[blockIdx.x] = sm[tid];
}

__global__ void scan_partials_kernel(const int* __restrict__ bsum,
                                     int* __restrict__ boff, int nchunks) {
    __shared__ int sm[SCAN_CHUNK];
    int tid = threadIdx.x;
    int v = (tid < nchunks) ? bsum[tid] : 0;
    sm[tid] = v;
    __syncthreads();
    for (int o = 1; o < SCAN_CHUNK; o <<= 1) {
        int t = (tid >= o) ? sm[tid - o] : 0;
        __syncthreads();
        sm[tid] += t;
        __syncthreads();
    }
    if (tid < nchunks) boff[tid] = sm[tid] - v;          // exclusive
}

__global__ void add_offsets_kernel(int* __restrict__ off,
                                   const int* __restrict__ boff,
                                   int n, int n_edges) {
    int gid = blockIdx.x * SCAN_CHUNK + threadIdx.x;
    if (gid < n) off[gid] += boff[blockIdx.x];
    if (gid == 0) off[n] = n_edges;
}

// ---------------- per-edge coefficient + CSR scatter ------------------------
__global__ void scatter_kernel(const float* __restrict__ d,
                               const int* __restrict__ src,
                               const int* __restrict__ dst,
                               const float* __restrict__ sD,
                               const float* __restrict__ sS,
                               const int* __restrict__ off,
                               int* __restrict__ cur,
                               int2* __restrict__ pack,
                               int n_edges) {
    int e = blockIdx.x * blockDim.x + threadIdx.x;
    if (e >= n_edges) return;
    int s = src[e];
    int t = dst[e];
    float g = tanhf(sD[t] + sS[s]);
    float c = g * d[t] * d[s];
    int p = off[t] + atomicAdd(&cur[t], 1);
    pack[p] = make_int2(s, __float_as_int(c));
}

// ---------------- pull-reduce: one wave per dst node ------------------------
__global__ void gather_kernel(const float* __restrict__ h,
                              const int* __restrict__ off,
                              const int2* __restrict__ pack,
                              float* __restrict__ z,
                              int n_nodes) {
    int gid  = blockIdx.x * blockDim.x + threadIdx.x;
    int node = gid >> 6;
    int lane = threadIdx.x & 63;
    if (node >= n_nodes) return;

    int beg = off[node];
    int end = off[node + 1];
    float acc = 0.f;
    for (int j = beg; j < end; ++j) {
        int2 pr = pack[j];                       // wave-uniform 8B broadcast
        acc = fmaf(h[(size_t)pr.x * IN_DIM + lane], __int_as_float(pr.y), acc);
    }
    z[(size_t)node * IN_DIM + lane] = acc;
}

// ---------------- fallback (atomic push) if workspace too small -------------
__global__ void edge_scatter_atomic_kernel(const float* __restrict__ h,
                                           const float* __restrict__ d,
                                           const int* __restrict__ src,
                                           const int* __restrict__ dst,
                                           const float* __restrict__ sD,
                                           const float* __restrict__ sS,
                                           float* __restrict__ z,
                                           int n_edges) {
    int gid  = blockIdx.x * blockDim.x + threadIdx.x;
    int e    = gid >> 6;
    int lane = threadIdx.x & 63;
    if (e >= n_edges) return;
    int s = src[e];
    int t = dst[e];
    float g = tanhf(sD[t] + sS[s]);
    float c = g * d[t] * d[s];
    atomicAdd(&z[t * IN_DIM + lane], h[s * IN_DIM + lane] * c);
}

extern "C" void kernel_launch(void* const* d_in, const int* in_sizes, int n_in,
                              void* d_out, int out_size, void* d_ws, size_t ws_size,
                              hipStream_t stream) {
    const float* h      = (const float*)d_in[0];
    const float* d      = (const float*)d_in[1];
    const int*   src    = (const int*)d_in[2];
    const int*   dst    = (const int*)d_in[3];
    const float* gate_w = (const float*)d_in[4];
    const float* gate_b = (const float*)d_in[5];

    const int n_nodes = in_sizes[1];   // d: one per node
    const int n_edges = in_sizes[2];   // src: one per edge
    float* z = (float*)d_out;

    const int nchunks = (n_nodes + SCAN_CHUNK - 1) / SCAN_CHUNK;   // 196 for 50k

    // workspace layout (pack first for 8B alignment)
    size_t need = (size_t)n_edges * sizeof(int2)
                + (size_t)(5 * n_nodes + 1 + 2 * nchunks) * sizeof(int);

    if (ws_size < need || nchunks > SCAN_CHUNK) {
        // fallback: original atomic path
        float* sD = (float*)d_ws;
        float* sS = sD + n_nodes;
        hipMemsetAsync(z, 0, (size_t)out_size * sizeof(float), stream);
        {
            int total = n_nodes * 64, threads = 256;
            node_scores_kernel<<<(total + threads - 1) / threads, threads, 0, stream>>>(
                h, gate_w, gate_b, sD, sS, n_nodes);
        }
        {
            long long total = (long long)n_edges * 64;
            int threads = 256;
            edge_scatter_atomic_kernel<<<(int)((total + threads - 1) / threads), threads, 0, stream>>>(
                h, d, src, dst, sD, sS, z, n_edges);
        }
        return;
    }

    int2*  pack = (int2*)d_ws;
    float* sD   = (float*)(pack + n_edges);
    float* sS   = sD + n_nodes;
    int*   cnt  = (int*)(sS + n_nodes);
    int*   off  = cnt + n_nodes;          // n_nodes + 1
    int*   cur  = off + n_nodes + 1;
    int*   bsum = cur + n_nodes;
    int*   boff = bsum + nchunks;

    hipMemsetAsync(cnt, 0, (size_t)n_nodes * sizeof(int), stream);
    hipMemsetAsync(cur, 0, (size_t)n_nodes * sizeof(int), stream);

    {   // node scores
        int total = n_nodes * 64, threads = 256;
        node_scores_kernel<<<(total + threads - 1) / threads, threads, 0, stream>>>(
            h, gate_w, gate_b, sD, sS, n_nodes);
    }
    {   // histogram of dst
        int threads = 256;
        hist_kernel<<<(n_edges + threads - 1) / threads, threads, 0, stream>>>(
            dst, cnt, n_edges);
    }
    // exclusive scan -> off
    scan_blocks_kernel<<<nchunks, SCAN_CHUNK, 0, stream>>>(cnt, off, bsum, n_nodes);
    scan_partials_kernel<<<1, SCAN_CHUNK, 0, stream>>>(bsum, boff, nchunks);
    add_offsets_kernel<<<nchunks, SCAN_CHUNK, 0, stream>>>(off, boff, n_nodes, n_edges);

    {   // per-edge coefficient + CSR scatter
        int threads = 256;
        scatter_kernel<<<(n_edges + threads - 1) / threads, threads, 0, stream>>>(
            d, src, dst, sD, sS, off, cur, pack, n_edges);
    }
    {   // pull-reduce, one wave per node, writes z exactly once
        long long total = (long long)n_nodes * 64;
        int threads = 256;
        gather_kernel<<<(int)((total + threads - 1) / threads), threads, 0, stream>>>(
            h, off, pack, z, n_nodes);
    }
}

// Round 3
// 158.499 us; speedup vs baseline: 1.3381x; 1.1658x over previous
//
#include <hip/hip_runtime.h>
#include <cmath>

#define IN_DIM 64
#define SCAN_CHUNK 256

// ---- node pass: pairD[i] = (h[i]·w_dst + b, d[i]), pairS[i] = (h[i]·w_src, d[i])
__global__ void node_scores_kernel(const float* __restrict__ h,
                                   const float* __restrict__ d,
                                   const float* __restrict__ gate_w,
                                   const float* __restrict__ gate_b,
                                   float2* __restrict__ pairD,
                                   float2* __restrict__ pairS,
                                   int n_nodes) {
    int gid  = blockIdx.x * blockDim.x + threadIdx.x;
    int node = gid >> 6;
    int lane = threadIdx.x & 63;
    if (node >= n_nodes) return;

    float hv = h[node * IN_DIM + lane];
    float pd = hv * gate_w[lane];            // w_dst = gate_w[:64]
    float ps = hv * gate_w[IN_DIM + lane];   // w_src = gate_w[64:]

    #pragma unroll
    for (int off = 32; off > 0; off >>= 1) {
        pd += __shfl_xor(pd, off, 64);
        ps += __shfl_xor(ps, off, 64);
    }
    if (lane == 0) {
        float dv = d[node];
        pairD[node] = make_float2(pd + gate_b[0], dv);  // bias folded into s_dst
        pairS[node] = make_float2(ps, dv);
    }
}

// ---- histogram of dst ------------------------------------------------------
__global__ void hist_kernel(const int* __restrict__ dst, int* __restrict__ cnt,
                            int n_edges) {
    int e = blockIdx.x * blockDim.x + threadIdx.x;
    if (e < n_edges) atomicAdd(&cnt[dst[e]], 1);
}

// ---- 3-step exclusive scan -------------------------------------------------
__global__ void scan_blocks_kernel(const int* __restrict__ cnt,
                                   int* __restrict__ off,
                                   int* __restrict__ bsum, int n) {
    __shared__ int sm[SCAN_CHUNK];
    int tid = threadIdx.x;
    int gid = blockIdx.x * SCAN_CHUNK + tid;
    int v = (gid < n) ? cnt[gid] : 0;
    sm[tid] = v;
    __syncthreads();
    for (int o = 1; o < SCAN_CHUNK; o <<= 1) {
        int t = (tid >= o) ? sm[tid - o] : 0;
        __syncthreads();
        sm[tid] += t;
        __syncthreads();
    }
    if (gid < n) off[gid] = sm[tid] - v;
    if (tid == SCAN_CHUNK - 1) bsum[blockIdx.x] = sm[tid];
}

__global__ void scan_partials_kernel(const int* __restrict__ bsum,
                                     int* __restrict__ boff, int nchunks) {
    __shared__ int sm[SCAN_CHUNK];
    int tid = threadIdx.x;
    int v = (tid < nchunks) ? bsum[tid] : 0;
    sm[tid] = v;
    __syncthreads();
    for (int o = 1; o < SCAN_CHUNK; o <<= 1) {
        int t = (tid >= o) ? sm[tid - o] : 0;
        __syncthreads();
        sm[tid] += t;
        __syncthreads();
    }
    if (tid < nchunks) boff[tid] = sm[tid] - v;
}

__global__ void add_offsets_kernel(int* __restrict__ off,
                                   int* __restrict__ cur,
                                   const int* __restrict__ boff,
                                   int n, int n_edges) {
    int gid = blockIdx.x * SCAN_CHUNK + threadIdx.x;
    if (gid < n) {
        int v = off[gid] + boff[blockIdx.x];
        off[gid] = v;
        cur[gid] = v;            // cur starts at off -> scatter needs no off load
    }
    if (gid == 0) off[n] = n_edges;
}

// ---- CSR fill: pack[slot] = src index only ---------------------------------
__global__ void scatter_kernel(const int* __restrict__ src,
                               const int* __restrict__ dst,
                               int* __restrict__ cur,
                               int* __restrict__ pack,
                               int n_edges) {
    int e = blockIdx.x * blockDim.x + threadIdx.x;
    if (e >= n_edges) return;
    int p = atomicAdd(&cur[dst[e]], 1);
    pack[p] = src[e];
}

// ---- pull-reduce: wave per node, 4 edge-slots x float4 ---------------------
__global__ void gather_kernel(const float* __restrict__ h,
                              const float2* __restrict__ pairD,
                              const float2* __restrict__ pairS,
                              const int* __restrict__ off,
                              const int* __restrict__ pack,
                              float* __restrict__ z,
                              int n_nodes) {
    int gid  = blockIdx.x * blockDim.x + threadIdx.x;
    int node = gid >> 6;
    int lane = threadIdx.x & 63;
    if (node >= n_nodes) return;

    int slot = lane >> 4;      // 0..3 : which edge of the group of 4
    int quad = lane & 15;      // feature quad: floats [quad*4, quad*4+4)

    int beg = off[node];
    int end = off[node + 1];
    float2 pd = pairD[node];   // (sD+b, d[t]) — wave-uniform

    float4 acc = make_float4(0.f, 0.f, 0.f, 0.f);
    for (int base = beg; base < end; base += 4) {
        int j  = base + slot;
        bool v = (j < end);
        int  s = v ? pack[j] : 0;
        float2 ps = pairS[s];                       // (sS, d[s]) broadcast 8B
        float c = v ? tanhf(pd.x + ps.x) * ps.y : 0.f;
        const float4 hv = *reinterpret_cast<const float4*>(
            &h[(size_t)s * IN_DIM + quad * 4]);
        acc.x = fmaf(hv.x, c, acc.x);
        acc.y = fmaf(hv.y, c, acc.y);
        acc.z = fmaf(hv.z, c, acc.z);
        acc.w = fmaf(hv.w, c, acc.w);
    }

    // reduce across the 4 slots (lane bits 4 and 5)
    acc.x += __shfl_xor(acc.x, 16, 64);
    acc.y += __shfl_xor(acc.y, 16, 64);
    acc.z += __shfl_xor(acc.z, 16, 64);
    acc.w += __shfl_xor(acc.w, 16, 64);
    acc.x += __shfl_xor(acc.x, 32, 64);
    acc.y += __shfl_xor(acc.y, 32, 64);
    acc.z += __shfl_xor(acc.z, 32, 64);
    acc.w += __shfl_xor(acc.w, 32, 64);

    if (slot == 0) {
        acc.x *= pd.y; acc.y *= pd.y; acc.z *= pd.y; acc.w *= pd.y;  // * d[t]
        *reinterpret_cast<float4*>(&z[(size_t)node * IN_DIM + quad * 4]) = acc;
    }
}

// ---- fallback (atomic push) if workspace too small -------------------------
__global__ void edge_scatter_atomic_kernel(const float* __restrict__ h,
                                           const int* __restrict__ src,
                                           const int* __restrict__ dst,
                                           const float2* __restrict__ pairD,
                                           const float2* __restrict__ pairS,
                                           float* __restrict__ z,
                                           int n_edges) {
    int gid  = blockIdx.x * blockDim.x + threadIdx.x;
    int e    = gid >> 6;
    int lane = threadIdx.x & 63;
    if (e >= n_edges) return;
    int s = src[e];
    int t = dst[e];
    float2 pt = pairD[t];
    float2 ps = pairS[s];
    float c = tanhf(pt.x + ps.x) * pt.y * ps.y;
    atomicAdd(&z[t * IN_DIM + lane], h[s * IN_DIM + lane] * c);
}

extern "C" void kernel_launch(void* const* d_in, const int* in_sizes, int n_in,
                              void* d_out, int out_size, void* d_ws, size_t ws_size,
                              hipStream_t stream) {
    const float* h      = (const float*)d_in[0];
    const float* d      = (const float*)d_in[1];
    const int*   src    = (const int*)d_in[2];
    const int*   dst    = (const int*)d_in[3];
    const float* gate_w = (const float*)d_in[4];
    const float* gate_b = (const float*)d_in[5];

    const int n_nodes = in_sizes[1];   // d: one per node
    const int n_edges = in_sizes[2];   // src: one per edge
    float* z = (float*)d_out;

    const int nchunks = (n_nodes + SCAN_CHUNK - 1) / SCAN_CHUNK;

    // workspace layout: pairD, pairS (8B aligned), pack, cnt, off, cur, bsum, boff
    size_t need = (size_t)n_nodes * 2 * sizeof(float2)
                + (size_t)n_edges * sizeof(int)
                + (size_t)(3 * n_nodes + 1 + 2 * nchunks) * sizeof(int);

    if (ws_size < need || nchunks > SCAN_CHUNK) {
        // fallback: atomic push
        float2* pairD = (float2*)d_ws;
        float2* pairS = pairD + n_nodes;
        hipMemsetAsync(z, 0, (size_t)out_size * sizeof(float), stream);
        {
            int total = n_nodes * 64, threads = 256;
            node_scores_kernel<<<(total + threads - 1) / threads, threads, 0, stream>>>(
                h, d, gate_w, gate_b, pairD, pairS, n_nodes);
        }
        {
            long long total = (long long)n_edges * 64;
            int threads = 256;
            edge_scatter_atomic_kernel<<<(int)((total + threads - 1) / threads), threads, 0, stream>>>(
                h, src, dst, pairD, pairS, z, n_edges);
        }
        return;
    }

    float2* pairD = (float2*)d_ws;
    float2* pairS = pairD + n_nodes;
    int*    pack  = (int*)(pairS + n_nodes);
    int*    cnt   = pack + n_edges;
    int*    off   = cnt + n_nodes;       // n_nodes + 1
    int*    cur   = off + n_nodes + 1;
    int*    bsum  = cur + n_nodes;
    int*    boff  = bsum + nchunks;

    hipMemsetAsync(cnt, 0, (size_t)n_nodes * sizeof(int), stream);

    {   // node scores + d pairs
        int total = n_nodes * 64, threads = 256;
        node_scores_kernel<<<(total + threads - 1) / threads, threads, 0, stream>>>(
            h, d, gate_w, gate_b, pairD, pairS, n_nodes);
    }
    {   // histogram of dst
        int threads = 256;
        hist_kernel<<<(n_edges + threads - 1) / threads, threads, 0, stream>>>(
            dst, cnt, n_edges);
    }
    // exclusive scan -> off, cur
    scan_blocks_kernel<<<nchunks, SCAN_CHUNK, 0, stream>>>(cnt, off, bsum, n_nodes);
    scan_partials_kernel<<<1, SCAN_CHUNK, 0, stream>>>(bsum, boff, nchunks);
    add_offsets_kernel<<<nchunks, SCAN_CHUNK, 0, stream>>>(off, cur, boff, n_nodes, n_edges);

    {   // CSR fill (src index only)
        int threads = 256;
        scatter_kernel<<<(n_edges + threads - 1) / threads, threads, 0, stream>>>(
            src, dst, cur, pack, n_edges);
    }
    {   // pull-reduce
        long long total = (long long)n_nodes * 64;
        int threads = 256;
        gather_kernel<<<(int)((total + threads - 1) / threads), threads, 0, stream>>>(
            h, pairD, pairS, off, pack, z, n_nodes);
    }
}